// Round 1
// baseline (1218.642 us; speedup 1.0000x reference)
//
#include <hip/hip_runtime.h>
#include <math.h>

constexpr int T = 4096;
constexpr int C = 1024;
constexpr int D = 256;
constexpr int VOCAB = 32000;

// ---------------------------------------------------------------------------
// Kernel 1: q = x @ Wq, k = x @ Wk  (fp32, 64x64 tiles, 4x4 micro-tiles)
// grid (T/64, D/64, 2), block 256
// ---------------------------------------------------------------------------
__global__ __launch_bounds__(256) void qk_gemm_kernel(
    const float* __restrict__ x,
    const float* __restrict__ Wq,
    const float* __restrict__ Wk,
    float* __restrict__ q,
    float* __restrict__ k)
{
    const float* W = (blockIdx.z == 0) ? Wq : Wk;
    float* outp    = (blockIdx.z == 0) ? q : k;
    const int m0 = blockIdx.x * 64;
    const int n0 = blockIdx.y * 64;

    __shared__ float xs[64][65];   // +1 pad: conflict-free column reads
    __shared__ float ws[64][65];

    const int tid = threadIdx.x;
    const int tx = tid & 15;       // 0..15
    const int ty = tid >> 4;       // 0..15

    float acc[4][4] = {};

    for (int k0 = 0; k0 < C; k0 += 64) {
        // stage 64x64 tiles (coalesced: consecutive tid -> consecutive col)
        #pragma unroll
        for (int p = 0; p < 16; ++p) {
            const int e = p * 256 + tid;
            const int r = e >> 6, cc = e & 63;
            xs[r][cc] = x[(size_t)(m0 + r) * C + k0 + cc];
            ws[r][cc] = W[(size_t)(k0 + r) * D + n0 + cc];
        }
        __syncthreads();

        #pragma unroll 8
        for (int kk = 0; kk < 64; ++kk) {
            float a[4], b[4];
            #pragma unroll
            for (int i = 0; i < 4; ++i) a[i] = xs[ty * 4 + i][kk];
            #pragma unroll
            for (int j = 0; j < 4; ++j) b[j] = ws[kk][tx * 4 + j];
            #pragma unroll
            for (int i = 0; i < 4; ++i)
                #pragma unroll
                for (int j = 0; j < 4; ++j)
                    acc[i][j] += a[i] * b[j];
        }
        __syncthreads();
    }

    #pragma unroll
    for (int i = 0; i < 4; ++i)
        #pragma unroll
        for (int j = 0; j < 4; ++j)
            outp[(size_t)(m0 + ty * 4 + i) * D + n0 + tx * 4 + j] = acc[i][j];
}

// ---------------------------------------------------------------------------
// Kernel 2: per causal 64x64 tile of c = (q @ k^T) / 256, scatter-add
// columns into out[t, idx[j]].  grid = T/64*(T/64+1)/2 blocks, block 256.
// ---------------------------------------------------------------------------
__global__ __launch_bounds__(256) void attn_scatter_kernel(
    const float* __restrict__ q,
    const float* __restrict__ k,
    const int* __restrict__ idx,
    float* __restrict__ out)
{
    // linear block id -> lower-triangular (ti, tj), tj <= ti
    const int bid = blockIdx.x;
    int ti = (int)((sqrtf(8.0f * (float)bid + 1.0f) - 1.0f) * 0.5f);
    while ((ti + 1) * (ti + 2) / 2 <= bid) ++ti;
    while (ti * (ti + 1) / 2 > bid) --ti;
    const int tj = bid - ti * (ti + 1) / 2;

    __shared__ float qs[64][65];
    __shared__ float ks[64][65];
    __shared__ int   idxs[64];

    const int tid = threadIdx.x;
    const int tx = tid & 15;
    const int ty = tid >> 4;

    if (tid < 64) idxs[tid] = idx[tj * 64 + tid];

    float acc[4][4] = {};

    for (int d0 = 0; d0 < D; d0 += 64) {
        #pragma unroll
        for (int p = 0; p < 16; ++p) {
            const int e = p * 256 + tid;
            const int r = e >> 6, cc = e & 63;
            qs[r][cc] = q[(size_t)(ti * 64 + r) * D + d0 + cc];
            ks[r][cc] = k[(size_t)(tj * 64 + r) * D + d0 + cc];
        }
        __syncthreads();

        #pragma unroll 8
        for (int dd = 0; dd < 64; ++dd) {
            float a[4], b[4];
            #pragma unroll
            for (int i = 0; i < 4; ++i) a[i] = qs[ty * 4 + i][dd];
            #pragma unroll
            for (int j = 0; j < 4; ++j) b[j] = ks[tx * 4 + j][dd];
            #pragma unroll
            for (int i = 0; i < 4; ++i)
                #pragma unroll
                for (int j = 0; j < 4; ++j)
                    acc[i][j] += a[i] * b[j];
        }
        __syncthreads();
    }

    const float scale = 1.0f / 256.0f;
    #pragma unroll
    for (int i = 0; i < 4; ++i) {
        const int t = ti * 64 + ty * 4 + i;
        float* orow = out + (size_t)t * VOCAB;
        #pragma unroll
        for (int j = 0; j < 4; ++j) {
            const int jg = tj * 64 + tx * 4 + j;
            if (jg <= t) {
                atomicAdd(&orow[idxs[tx * 4 + j]], acc[i][j] * scale);
            }
        }
    }
}

// ---------------------------------------------------------------------------
extern "C" void kernel_launch(void* const* d_in, const int* in_sizes, int n_in,
                              void* d_out, int out_size, void* d_ws, size_t ws_size,
                              hipStream_t stream)
{
    const float* x  = (const float*)d_in[0];
    const int*   idx = (const int*)d_in[1];
    const float* Wq = (const float*)d_in[2];
    const float* Wk = (const float*)d_in[3];
    float* out = (float*)d_out;

    float* q = (float*)d_ws;                 // T*D fp32 = 4 MB
    float* k = q + (size_t)T * D;            // 4 MB

    // out is poisoned before every call: zero all 524 MB (capture-safe)
    hipMemsetAsync(d_out, 0, (size_t)out_size * sizeof(float), stream);

    qk_gemm_kernel<<<dim3(T / 64, D / 64, 2), 256, 0, stream>>>(x, Wq, Wk, q, k);

    const int ntiles = (T / 64) * (T / 64 + 1) / 2;   // 2080 causal tiles
    attn_scatter_kernel<<<dim3(ntiles), 256, 0, stream>>>(q, k, idx, out);
}

// Round 2
// 954.881 us; speedup vs baseline: 1.2762x; 1.2762x over previous
//
#include <hip/hip_runtime.h>
#include <math.h>

constexpr int T = 4096;
constexpr int C = 1024;
constexpr int D = 256;
constexpr int VOCAB = 32000;
constexpr int VHALF = VOCAB / 2;       // 16000 slots -> 62.5 KB LDS (< 64 KB static limit)
constexpr int NT = T / 64;             // 64 row/col tiles
constexpr int NTILES = NT * (NT + 1) / 2;  // 2080 causal tiles

// ---------------------------------------------------------------------------
// Kernel 1: q = x @ Wq, k = x @ Wk  (fp32, 64x64 tiles, 4x4 micro-tiles)
// grid (T/64, D/64, 2), block 256
// ---------------------------------------------------------------------------
__global__ __launch_bounds__(256) void qk_gemm_kernel(
    const float* __restrict__ x,
    const float* __restrict__ Wq,
    const float* __restrict__ Wk,
    float* __restrict__ q,
    float* __restrict__ k)
{
    const float* W = (blockIdx.z == 0) ? Wq : Wk;
    float* outp    = (blockIdx.z == 0) ? q : k;
    const int m0 = blockIdx.x * 64;
    const int n0 = blockIdx.y * 64;

    __shared__ float xs[64][65];
    __shared__ float ws[64][65];

    const int tid = threadIdx.x;
    const int tx = tid & 15;
    const int ty = tid >> 4;

    float acc[4][4] = {};

    for (int k0 = 0; k0 < C; k0 += 64) {
        #pragma unroll
        for (int p = 0; p < 16; ++p) {
            const int e = p * 256 + tid;
            const int r = e >> 6, cc = e & 63;
            xs[r][cc] = x[(size_t)(m0 + r) * C + k0 + cc];
            ws[r][cc] = W[(size_t)(k0 + r) * D + n0 + cc];
        }
        __syncthreads();

        #pragma unroll 8
        for (int kk = 0; kk < 64; ++kk) {
            float a[4], b[4];
            #pragma unroll
            for (int i = 0; i < 4; ++i) a[i] = xs[ty * 4 + i][kk];
            #pragma unroll
            for (int j = 0; j < 4; ++j) b[j] = ws[kk][tx * 4 + j];
            #pragma unroll
            for (int i = 0; i < 4; ++i)
                #pragma unroll
                for (int j = 0; j < 4; ++j)
                    acc[i][j] += a[i] * b[j];
        }
        __syncthreads();
    }

    #pragma unroll
    for (int i = 0; i < 4; ++i)
        #pragma unroll
        for (int j = 0; j < 4; ++j)
            outp[(size_t)(m0 + ty * 4 + i) * D + n0 + tx * 4 + j] = acc[i][j];
}

// ---------------------------------------------------------------------------
// Kernel 2: causal 64x64 tiles of c = (q @ k^T)/256, masked+scaled, stored
// packed: tile (ti,tj), tj<=ti at slot s = ti*(ti+1)/2+tj, row-major 64x64.
// grid = NTILES, block 256. No atomics.
// ---------------------------------------------------------------------------
__global__ __launch_bounds__(256) void qkt_tiles_kernel(
    const float* __restrict__ q,
    const float* __restrict__ k,
    float* __restrict__ c_ws)
{
    const int bid = blockIdx.x;
    int ti = (int)((sqrtf(8.0f * (float)bid + 1.0f) - 1.0f) * 0.5f);
    while ((ti + 1) * (ti + 2) / 2 <= bid) ++ti;
    while (ti * (ti + 1) / 2 > bid) --ti;
    const int tj = bid - ti * (ti + 1) / 2;

    __shared__ float qs[64][65];
    __shared__ float ks[64][65];

    const int tid = threadIdx.x;
    const int tx = tid & 15;
    const int ty = tid >> 4;

    float acc[4][4] = {};

    for (int d0 = 0; d0 < D; d0 += 64) {
        #pragma unroll
        for (int p = 0; p < 16; ++p) {
            const int e = p * 256 + tid;
            const int r = e >> 6, cc = e & 63;
            qs[r][cc] = q[(size_t)(ti * 64 + r) * D + d0 + cc];
            ks[r][cc] = k[(size_t)(tj * 64 + r) * D + d0 + cc];
        }
        __syncthreads();

        #pragma unroll 8
        for (int dd = 0; dd < 64; ++dd) {
            float a[4], b[4];
            #pragma unroll
            for (int i = 0; i < 4; ++i) a[i] = qs[ty * 4 + i][dd];
            #pragma unroll
            for (int j = 0; j < 4; ++j) b[j] = ks[tx * 4 + j][dd];
            #pragma unroll
            for (int i = 0; i < 4; ++i)
                #pragma unroll
                for (int j = 0; j < 4; ++j)
                    acc[i][j] += a[i] * b[j];
        }
        __syncthreads();
    }

    const float scale = 1.0f / 256.0f;
    float* tile = c_ws + (size_t)bid * 4096;   // 64x64 row-major
    #pragma unroll
    for (int i = 0; i < 4; ++i) {
        const int t = ti * 64 + ty * 4 + i;
        float4 v;
        const int jbase = tj * 64 + tx * 4;
        v.x = (jbase + 0 <= t) ? acc[i][0] * scale : 0.0f;
        v.y = (jbase + 1 <= t) ? acc[i][1] * scale : 0.0f;
        v.z = (jbase + 2 <= t) ? acc[i][2] * scale : 0.0f;
        v.w = (jbase + 3 <= t) ? acc[i][3] * scale : 0.0f;
        *(float4*)(tile + (ty * 4 + i) * 64 + tx * 4) = v;
    }
}

// ---------------------------------------------------------------------------
// Kernel 3: one block per (row t, vocab half). LDS histogram accumulation,
// then dense streaming write of the half-row. Replaces memset + global atomics.
// grid (T, 2), block 256.
// ---------------------------------------------------------------------------
__global__ __launch_bounds__(256) void row_scatter_kernel(
    const float* __restrict__ c_ws,
    const int* __restrict__ idx,
    float* __restrict__ out)
{
    __shared__ float4 hist4[VHALF / 4];        // 62.5 KB
    float* hist = (float*)hist4;

    const int t  = blockIdx.x;
    const int lo = blockIdx.y * VHALF;
    const int hi = lo + VHALF;
    const int tid = threadIdx.x;

    // zero histogram
    const float4 z4 = {0.0f, 0.0f, 0.0f, 0.0f};
    for (int v = tid; v < VHALF / 4; v += 256) hist4[v] = z4;
    __syncthreads();

    const int ti = t >> 6;
    const int il = t & 63;
    const int jmax = (ti + 1) * 64;            // diag tile has masked zeros
    const size_t row_base = (size_t)ti * (ti + 1) / 2;

    for (int j = tid; j < jmax; j += 256) {
        const int tj = j >> 6;
        const int jl = j & 63;
        const float val = c_ws[(row_base + tj) * 4096 + il * 64 + jl];
        const int v = idx[j];
        if (v >= lo && v < hi) {
            atomicAdd(&hist[v - lo], val);
        }
    }
    __syncthreads();

    // stream the half-row out
    float4* orow = (float4*)(out + (size_t)t * VOCAB + lo);
    for (int v = tid; v < VHALF / 4; v += 256) orow[v] = hist4[v];
}

// ---------------------------------------------------------------------------
extern "C" void kernel_launch(void* const* d_in, const int* in_sizes, int n_in,
                              void* d_out, int out_size, void* d_ws, size_t ws_size,
                              hipStream_t stream)
{
    const float* x   = (const float*)d_in[0];
    const int*   idx = (const int*)d_in[1];
    const float* Wq  = (const float*)d_in[2];
    const float* Wk  = (const float*)d_in[3];
    float* out = (float*)d_out;

    // ws layout: q (4 MB) | k (4 MB) | c tiles (34.1 MB)  => 42.1 MB total
    float* q    = (float*)d_ws;
    float* k    = q + (size_t)T * D;
    float* c_ws = k + (size_t)T * D;

    qk_gemm_kernel<<<dim3(T / 64, D / 64, 2), 256, 0, stream>>>(x, Wq, Wk, q, k);
    qkt_tiles_kernel<<<dim3(NTILES), 256, 0, stream>>>(q, k, c_ws);
    row_scatter_kernel<<<dim3(T, 2), 256, 0, stream>>>(c_ws, idx, out);
}

// Round 3
// 587.005 us; speedup vs baseline: 2.0760x; 1.6267x over previous
//
#include <hip/hip_runtime.h>
#include <math.h>

constexpr int T = 4096;
constexpr int C = 1024;
constexpr int D = 256;
constexpr int VOCAB = 32000;
constexpr int VHALF = VOCAB / 2;           // 16000 floats = 62.5 KB LDS
constexpr int NT = T / 64;
constexpr int NTILES = NT * (NT + 1) / 2;  // 2080 causal tiles

typedef __attribute__((ext_vector_type(8))) short bf16x8;
typedef __attribute__((ext_vector_type(4))) float f32x4;

__device__ inline unsigned short f2bf(float f) {
    union { float f; unsigned int u; } v; v.f = f;
    unsigned int u = v.u + 0x7FFFu + ((v.u >> 16) & 1u);   // RTNE
    return (unsigned short)(u >> 16);
}

// ---------------------------------------------------------------------------
// Kernel 0a: x fp32 -> bf16.  grid 2048 x 256, 8 elems/thread.
// ---------------------------------------------------------------------------
__global__ __launch_bounds__(256) void convert_x_kernel(
    const float* __restrict__ x, unsigned short* __restrict__ xb)
{
    const int i = (blockIdx.x * 256 + threadIdx.x) * 8;
    float4 a = *(const float4*)(x + i);
    float4 b = *(const float4*)(x + i + 4);
    union { bf16x8 v; unsigned short s[8]; } o;
    o.s[0] = f2bf(a.x); o.s[1] = f2bf(a.y); o.s[2] = f2bf(a.z); o.s[3] = f2bf(a.w);
    o.s[4] = f2bf(b.x); o.s[5] = f2bf(b.y); o.s[6] = f2bf(b.z); o.s[7] = f2bf(b.w);
    *(bf16x8*)(xb + i) = o.v;
}

// ---------------------------------------------------------------------------
// Kernel 0b: W [C][D] fp32 -> WT [2D][C] bf16 (transposed, q|k stacked).
// grid (C/64, D/64, 2), block 256.
// ---------------------------------------------------------------------------
__global__ __launch_bounds__(256) void transpose_w_kernel(
    const float* __restrict__ Wq, const float* __restrict__ Wk,
    unsigned short* __restrict__ WT)
{
    const float* W = blockIdx.z ? Wk : Wq;
    const int k0 = blockIdx.x * 64, n0 = blockIdx.y * 64;
    __shared__ float tile[64][65];
    const int tid = threadIdx.x;
    #pragma unroll
    for (int p = 0; p < 16; ++p) {
        const int e = p * 256 + tid;
        const int r = e >> 6, c = e & 63;
        tile[c][r] = W[(size_t)(k0 + r) * D + n0 + c];
    }
    __syncthreads();
    #pragma unroll
    for (int p = 0; p < 2; ++p) {
        const int e = p * 256 + tid;
        const int rr = e >> 3, cc = e & 7;
        union { bf16x8 v; unsigned short s[8]; } o;
        #pragma unroll
        for (int i = 0; i < 8; ++i) o.s[i] = f2bf(tile[rr][cc * 8 + i]);
        *(bf16x8*)(WT + (size_t)(blockIdx.z * D + n0 + rr) * C + k0 + cc * 8) = o.v;
    }
}

// ---------------------------------------------------------------------------
// Kernel 1: qk[T][512] bf16 = xb[T][C] @ WT[512][C]^T   (MFMA 16x16x32 bf16)
// 64x64 block tile, 4 waves 2x2, K-step 64, XOR-swizzled LDS.
// ---------------------------------------------------------------------------
__global__ __launch_bounds__(256) void qk_mfma_kernel(
    const unsigned short* __restrict__ xb,
    const unsigned short* __restrict__ WT,
    unsigned short* __restrict__ qk)
{
    const int m0 = blockIdx.x * 64, n0 = blockIdx.y * 64;
    __shared__ __align__(16) unsigned short As[64 * 64];
    __shared__ __align__(16) unsigned short Bs[64 * 64];
    const int tid = threadIdx.x;
    const int wave = tid >> 6, lane = tid & 63;
    const int quad = lane >> 4, lr = lane & 15;
    const int wm = wave >> 1, wn = wave & 1;

    f32x4 acc[2][2] = {};

    for (int k0 = 0; k0 < C; k0 += 64) {
        #pragma unroll
        for (int p = 0; p < 2; ++p) {
            const int e = p * 256 + tid;
            const int r = e >> 3, c = e & 7, cs = c ^ (r & 7);
            *(bf16x8*)(As + r * 64 + cs * 8) =
                *(const bf16x8*)(xb + (size_t)(m0 + r) * C + k0 + c * 8);
            *(bf16x8*)(Bs + r * 64 + cs * 8) =
                *(const bf16x8*)(WT + (size_t)(n0 + r) * C + k0 + c * 8);
        }
        __syncthreads();
        #pragma unroll
        for (int kk = 0; kk < 64; kk += 32) {
            bf16x8 a[2], b[2];
            #pragma unroll
            for (int s = 0; s < 2; ++s) {
                const int ra = wm * 32 + s * 16 + lr;
                const int ca = ((kk >> 3) + quad) ^ (ra & 7);
                a[s] = *(const bf16x8*)(As + ra * 64 + ca * 8);
                const int rb = wn * 32 + s * 16 + lr;
                const int cb = ((kk >> 3) + quad) ^ (rb & 7);
                b[s] = *(const bf16x8*)(Bs + rb * 64 + cb * 8);
            }
            #pragma unroll
            for (int i = 0; i < 2; ++i)
                #pragma unroll
                for (int j = 0; j < 2; ++j)
                    acc[i][j] = __builtin_amdgcn_mfma_f32_16x16x32_bf16(
                        a[i], b[j], acc[i][j], 0, 0, 0);
        }
        __syncthreads();
    }

    #pragma unroll
    for (int i = 0; i < 2; ++i)
        #pragma unroll
        for (int j = 0; j < 2; ++j)
            #pragma unroll
            for (int r = 0; r < 4; ++r) {
                const int row = m0 + wm * 32 + i * 16 + quad * 4 + r;
                const int col = n0 + wn * 32 + j * 16 + lr;
                qk[(size_t)row * 512 + col] = f2bf(acc[i][j][r]);
            }
}

// ---------------------------------------------------------------------------
// Kernel 2: causal 64x64 tiles of c = (q @ k^T)/256, masked, fp32 packed.
// A = qk rows (q part, ld 512), B = qk rows + 256 (k part). K = 256.
// ---------------------------------------------------------------------------
__global__ __launch_bounds__(256) void qkt_mfma_kernel(
    const unsigned short* __restrict__ qk,
    float* __restrict__ c_ws)
{
    const int bid = blockIdx.x;
    int ti = (int)((sqrtf(8.0f * (float)bid + 1.0f) - 1.0f) * 0.5f);
    while ((ti + 1) * (ti + 2) / 2 <= bid) ++ti;
    while (ti * (ti + 1) / 2 > bid) --ti;
    const int tj = bid - ti * (ti + 1) / 2;

    __shared__ __align__(16) unsigned short As[64 * 64];
    __shared__ __align__(16) unsigned short Bs[64 * 64];
    const int tid = threadIdx.x;
    const int wave = tid >> 6, lane = tid & 63;
    const int quad = lane >> 4, lr = lane & 15;
    const int wm = wave >> 1, wn = wave & 1;

    f32x4 acc[2][2] = {};

    const unsigned short* qp = qk + (size_t)ti * 64 * 512;
    const unsigned short* kp = qk + (size_t)tj * 64 * 512 + 256;

    for (int k0 = 0; k0 < D; k0 += 64) {
        #pragma unroll
        for (int p = 0; p < 2; ++p) {
            const int e = p * 256 + tid;
            const int r = e >> 3, c = e & 7, cs = c ^ (r & 7);
            *(bf16x8*)(As + r * 64 + cs * 8) =
                *(const bf16x8*)(qp + (size_t)r * 512 + k0 + c * 8);
            *(bf16x8*)(Bs + r * 64 + cs * 8) =
                *(const bf16x8*)(kp + (size_t)r * 512 + k0 + c * 8);
        }
        __syncthreads();
        #pragma unroll
        for (int kk = 0; kk < 64; kk += 32) {
            bf16x8 a[2], b[2];
            #pragma unroll
            for (int s = 0; s < 2; ++s) {
                const int ra = wm * 32 + s * 16 + lr;
                const int ca = ((kk >> 3) + quad) ^ (ra & 7);
                a[s] = *(const bf16x8*)(As + ra * 64 + ca * 8);
                const int rb = wn * 32 + s * 16 + lr;
                const int cb = ((kk >> 3) + quad) ^ (rb & 7);
                b[s] = *(const bf16x8*)(Bs + rb * 64 + cb * 8);
            }
            #pragma unroll
            for (int i = 0; i < 2; ++i)
                #pragma unroll
                for (int j = 0; j < 2; ++j)
                    acc[i][j] = __builtin_amdgcn_mfma_f32_16x16x32_bf16(
                        a[i], b[j], acc[i][j], 0, 0, 0);
        }
        __syncthreads();
    }

    const float scale = 1.0f / 256.0f;
    float* tile = c_ws + (size_t)bid * 4096;
    #pragma unroll
    for (int i = 0; i < 2; ++i)
        #pragma unroll
        for (int j = 0; j < 2; ++j)
            #pragma unroll
            for (int r = 0; r < 4; ++r) {
                const int row = wm * 32 + i * 16 + quad * 4 + r;
                const int col = wn * 32 + j * 16 + lr;
                const int rg = ti * 64 + row, cg = tj * 64 + col;
                tile[row * 64 + col] = (cg <= rg) ? acc[i][j][r] * scale : 0.0f;
            }
}

// ---------------------------------------------------------------------------
// Kernel 3: one block per (row t, vocab half). LDS histogram + dense write.
// block 1024: 2 blocks/CU (LDS) x 16 waves = full occupancy.
// ---------------------------------------------------------------------------
__global__ __launch_bounds__(1024) void row_scatter_kernel(
    const float* __restrict__ c_ws,
    const int* __restrict__ idx,
    float* __restrict__ out)
{
    __shared__ float4 hist4[VHALF / 4];        // 62.5 KB
    float* hist = (float*)hist4;

    const int t  = blockIdx.x;
    const int lo = blockIdx.y * VHALF;
    const int tid = threadIdx.x;

    const float4 z4 = {0.0f, 0.0f, 0.0f, 0.0f};
    for (int v = tid; v < VHALF / 4; v += 1024) hist4[v] = z4;
    __syncthreads();

    const int ti = t >> 6;
    const int il = t & 63;
    const int jmax = (ti + 1) * 64;
    const size_t row_base = (size_t)ti * (ti + 1) / 2;

    const int j4 = tid * 4;
    if (j4 < jmax) {
        const int tj = j4 >> 6, jl = j4 & 63;
        const float4 vv = *(const float4*)(c_ws + (row_base + tj) * 4096 + il * 64 + jl);
        const int4  iv = *(const int4*)(idx + j4);
        int v0 = iv.x - lo, v1 = iv.y - lo, v2 = iv.z - lo, v3 = iv.w - lo;
        if ((unsigned)v0 < (unsigned)VHALF && vv.x != 0.0f) atomicAdd(&hist[v0], vv.x);
        if ((unsigned)v1 < (unsigned)VHALF && vv.y != 0.0f) atomicAdd(&hist[v1], vv.y);
        if ((unsigned)v2 < (unsigned)VHALF && vv.z != 0.0f) atomicAdd(&hist[v2], vv.z);
        if ((unsigned)v3 < (unsigned)VHALF && vv.w != 0.0f) atomicAdd(&hist[v3], vv.w);
    }
    __syncthreads();

    float4* orow = (float4*)(out + (size_t)t * VOCAB + lo);
    for (int v = tid; v < VHALF / 4; v += 1024) orow[v] = hist4[v];
}

// ---------------------------------------------------------------------------
extern "C" void kernel_launch(void* const* d_in, const int* in_sizes, int n_in,
                              void* d_out, int out_size, void* d_ws, size_t ws_size,
                              hipStream_t stream)
{
    const float* x   = (const float*)d_in[0];
    const int*   idx = (const int*)d_in[1];
    const float* Wq  = (const float*)d_in[2];
    const float* Wk  = (const float*)d_in[3];
    float* out = (float*)d_out;

    // ws: xb 8MB | WT 1MB | qk 4MB | c_ws 34.1MB
    unsigned short* xb = (unsigned short*)d_ws;
    unsigned short* WT = xb + (size_t)T * C;
    unsigned short* qk = WT + (size_t)2 * D * C;
    float* c_ws = (float*)(qk + (size_t)T * 2 * D);

    convert_x_kernel<<<dim3((T * C) / (256 * 8)), 256, 0, stream>>>(x, xb);
    transpose_w_kernel<<<dim3(C / 64, D / 64, 2), 256, 0, stream>>>(Wq, Wk, WT);
    qk_mfma_kernel<<<dim3(T / 64, (2 * D) / 64), 256, 0, stream>>>(xb, WT, qk);
    qkt_mfma_kernel<<<dim3(NTILES), 256, 0, stream>>>(qk, c_ws);
    row_scatter_kernel<<<dim3(T, 2), 1024, 0, stream>>>(c_ws, idx, out);
}

// Round 4
// 564.191 us; speedup vs baseline: 2.1600x; 1.0404x over previous
//
#include <hip/hip_runtime.h>
#include <math.h>

constexpr int T = 4096;
constexpr int C = 1024;
constexpr int D = 256;
constexpr int VOCAB = 32000;
constexpr int VQ = VOCAB / 4;              // 8000 floats = 31.25 KB LDS
constexpr int NT = T / 64;
constexpr int NTILES = NT * (NT + 1) / 2;  // 2080 causal tiles

typedef __attribute__((ext_vector_type(8))) short bf16x8;
typedef __attribute__((ext_vector_type(4))) float f32x4;

__device__ inline unsigned short f2bf(float f) {
    union { float f; unsigned int u; } v; v.f = f;
    unsigned int u = v.u + 0x7FFFu + ((v.u >> 16) & 1u);   // RTNE
    return (unsigned short)(u >> 16);
}
__device__ inline float bf2f(unsigned short s) {
    union { unsigned int u; float f; } v; v.u = ((unsigned int)s) << 16;
    return v.f;
}
// async global->LDS, 16B per lane; LDS dest = wave-uniform base + lane*16
__device__ inline void gl_lds16(const unsigned short* g, unsigned short* l) {
    __builtin_amdgcn_global_load_lds(
        (const __attribute__((address_space(1))) unsigned int*)g,
        (__attribute__((address_space(3))) unsigned int*)l, 16, 0, 0);
}

// ---------------------------------------------------------------------------
// Prep: blocks [0,2048): x fp32 -> bf16 (8 elems/thread)
//       blocks [2048,2176): W [C][D] fp32 -> WT [512][C] bf16 transposed
// ---------------------------------------------------------------------------
__global__ __launch_bounds__(256) void prep_kernel(
    const float* __restrict__ x,
    const float* __restrict__ Wq, const float* __restrict__ Wk,
    unsigned short* __restrict__ xb, unsigned short* __restrict__ WT)
{
    const int tid = threadIdx.x;
    if (blockIdx.x < 2048) {
        const int i = (blockIdx.x * 256 + tid) * 8;
        float4 a = *(const float4*)(x + i);
        float4 b = *(const float4*)(x + i + 4);
        union { bf16x8 v; unsigned short s[8]; } o;
        o.s[0] = f2bf(a.x); o.s[1] = f2bf(a.y); o.s[2] = f2bf(a.z); o.s[3] = f2bf(a.w);
        o.s[4] = f2bf(b.x); o.s[5] = f2bf(b.y); o.s[6] = f2bf(b.z); o.s[7] = f2bf(b.w);
        *(bf16x8*)(xb + i) = o.v;
    } else {
        const int bid = blockIdx.x - 2048;        // 128 blocks
        const int w  = bid >> 6;                  // 0=Wq, 1=Wk
        const int rem = bid & 63;
        const int k0 = (rem >> 2) * 64;           // 16 k-tiles
        const int n0 = (rem & 3) * 64;            // 4 n-tiles
        const float* W = w ? Wk : Wq;
        __shared__ float tile[64][65];
        #pragma unroll
        for (int p = 0; p < 16; ++p) {
            const int e = p * 256 + tid;
            const int r = e >> 6, c = e & 63;
            tile[c][r] = W[(size_t)(k0 + r) * D + n0 + c];
        }
        __syncthreads();
        #pragma unroll
        for (int p = 0; p < 2; ++p) {
            const int e = p * 256 + tid;
            const int rr = e >> 3, cc = e & 7;
            union { bf16x8 v; unsigned short s[8]; } o;
            #pragma unroll
            for (int i = 0; i < 8; ++i) o.s[i] = f2bf(tile[rr][cc * 8 + i]);
            *(bf16x8*)(WT + (size_t)(w * D + n0 + rr) * C + k0 + cc * 8) = o.v;
        }
    }
}

// ---------------------------------------------------------------------------
// Kernel 1: qk[T][512] bf16 = xb[T][C] @ WT[512][C]^T
// 64x64 tile, 4 waves 2x2, BK=64, raw K-major LDS + global_load_lds(16B).
// ---------------------------------------------------------------------------
__global__ __launch_bounds__(256) void qk_mfma_kernel(
    const unsigned short* __restrict__ xb,
    const unsigned short* __restrict__ WT,
    unsigned short* __restrict__ qk)
{
    const int m0 = blockIdx.x * 64, n0 = blockIdx.y * 64;
    __shared__ __align__(16) unsigned short As[64 * 64];
    __shared__ __align__(16) unsigned short Bs[64 * 64];
    const int tid = threadIdx.x;
    const int wave = tid >> 6, lane = tid & 63;
    const int quad = lane >> 4, lr = lane & 15;
    const int wm = wave >> 1, wn = wave & 1;
    const int rsub = lane >> 3, c8 = (lane & 7) * 8;   // staging lane map

    f32x4 acc[2][2] = {};

    for (int k0 = 0; k0 < C; k0 += 64) {
        #pragma unroll
        for (int q = 0; q < 2; ++q) {
            const int ch = wave * 2 + q;               // 0..7, 8 rows each
            const int r = ch * 8 + rsub;
            gl_lds16(xb + (size_t)(m0 + r) * C + k0 + c8, As + ch * 512);
            gl_lds16(WT + (size_t)(n0 + r) * C + k0 + c8, Bs + ch * 512);
        }
        __syncthreads();
        #pragma unroll
        for (int kk = 0; kk < 64; kk += 32) {
            bf16x8 a[2], b[2];
            #pragma unroll
            for (int s = 0; s < 2; ++s) {
                a[s] = *(const bf16x8*)(As + (wm * 32 + s * 16 + lr) * 64 + kk + quad * 8);
                b[s] = *(const bf16x8*)(Bs + (wn * 32 + s * 16 + lr) * 64 + kk + quad * 8);
            }
            #pragma unroll
            for (int i = 0; i < 2; ++i)
                #pragma unroll
                for (int j = 0; j < 2; ++j)
                    acc[i][j] = __builtin_amdgcn_mfma_f32_16x16x32_bf16(
                        a[i], b[j], acc[i][j], 0, 0, 0);
        }
        __syncthreads();
    }

    #pragma unroll
    for (int i = 0; i < 2; ++i)
        #pragma unroll
        for (int j = 0; j < 2; ++j)
            #pragma unroll
            for (int r = 0; r < 4; ++r) {
                const int row = m0 + wm * 32 + i * 16 + quad * 4 + r;
                const int col = n0 + wn * 32 + j * 16 + lr;
                qk[(size_t)row * 512 + col] = f2bf(acc[i][j][r]);
            }
}

// ---------------------------------------------------------------------------
// Kernel 2: causal 64x64 tiles of c = (q @ k^T)/256, masked, written as
// bf16 packed row-contiguous: row t=(ti*64+il) at tbase(ti)+il*len, len=(ti+1)*64.
// ---------------------------------------------------------------------------
__global__ __launch_bounds__(256) void qkt_mfma_kernel(
    const unsigned short* __restrict__ qk,
    unsigned short* __restrict__ cpack)
{
    const int bid = blockIdx.x;
    int ti = (int)((sqrtf(8.0f * (float)bid + 1.0f) - 1.0f) * 0.5f);
    while ((ti + 1) * (ti + 2) / 2 <= bid) ++ti;
    while (ti * (ti + 1) / 2 > bid) --ti;
    const int tj = bid - ti * (ti + 1) / 2;

    __shared__ __align__(16) unsigned short As[64 * 64];
    __shared__ __align__(16) unsigned short Bs[64 * 64];
    const int tid = threadIdx.x;
    const int wave = tid >> 6, lane = tid & 63;
    const int quad = lane >> 4, lr = lane & 15;
    const int wm = wave >> 1, wn = wave & 1;
    const int rsub = lane >> 3, c8 = (lane & 7) * 8;

    f32x4 acc[2][2] = {};

    const unsigned short* qp = qk + (size_t)ti * 64 * 512;        // q part
    const unsigned short* kp = qk + (size_t)tj * 64 * 512 + 256;  // k part

    for (int k0 = 0; k0 < D; k0 += 64) {
        #pragma unroll
        for (int q = 0; q < 2; ++q) {
            const int ch = wave * 2 + q;
            const int r = ch * 8 + rsub;
            gl_lds16(qp + (size_t)r * 512 + k0 + c8, As + ch * 512);
            gl_lds16(kp + (size_t)r * 512 + k0 + c8, Bs + ch * 512);
        }
        __syncthreads();
        #pragma unroll
        for (int kk = 0; kk < 64; kk += 32) {
            bf16x8 a[2], b[2];
            #pragma unroll
            for (int s = 0; s < 2; ++s) {
                a[s] = *(const bf16x8*)(As + (wm * 32 + s * 16 + lr) * 64 + kk + quad * 8);
                b[s] = *(const bf16x8*)(Bs + (wn * 32 + s * 16 + lr) * 64 + kk + quad * 8);
            }
            #pragma unroll
            for (int i = 0; i < 2; ++i)
                #pragma unroll
                for (int j = 0; j < 2; ++j)
                    acc[i][j] = __builtin_amdgcn_mfma_f32_16x16x32_bf16(
                        a[i], b[j], acc[i][j], 0, 0, 0);
        }
        __syncthreads();
    }

    // epilogue: mask+scale -> bf16 tile in LDS (reuse As), then packed write
    const float scale = 1.0f / 256.0f;
    unsigned short* Cs = As;
    #pragma unroll
    for (int i = 0; i < 2; ++i)
        #pragma unroll
        for (int j = 0; j < 2; ++j)
            #pragma unroll
            for (int r = 0; r < 4; ++r) {
                const int row = wm * 32 + i * 16 + quad * 4 + r;
                const int col = wn * 32 + j * 16 + lr;
                const int rg = ti * 64 + row, cg = tj * 64 + col;
                Cs[row * 64 + col] = f2bf((cg <= rg) ? acc[i][j][r] * scale : 0.0f);
            }
    __syncthreads();

    const size_t tbase = (size_t)4096 * ((size_t)ti * (ti + 1) / 2);
    const int len = (ti + 1) * 64;
    #pragma unroll
    for (int p = 0; p < 2; ++p) {
        const int cidx = p * 256 + tid;        // 512 chunks of 16B
        const int row = cidx >> 3, o8 = (cidx & 7) * 8;
        *(bf16x8*)(cpack + tbase + (size_t)row * len + tj * 64 + o8) =
            *(const bf16x8*)(Cs + row * 64 + o8);
    }
}

// ---------------------------------------------------------------------------
// Kernel 3: one block per (row t, vocab quarter). LDS histogram + dense
// nontemporal write. 31.25 KB LDS, 256 thr -> ~5 blocks/CU resident.
// ---------------------------------------------------------------------------
__global__ __launch_bounds__(256) void row_scatter_kernel(
    const unsigned short* __restrict__ cpack,
    const int* __restrict__ idx,
    float* __restrict__ out)
{
    __shared__ f32x4 hist4[VQ / 4];            // 31.25 KB
    float* hist = (float*)hist4;

    const int t  = blockIdx.x;
    const int lo = blockIdx.y * VQ;
    const int tid = threadIdx.x;

    const f32x4 z4 = {0.0f, 0.0f, 0.0f, 0.0f};
    for (int v = tid; v < VQ / 4; v += 256) hist4[v] = z4;
    __syncthreads();

    const int ti = t >> 6, il = t & 63;
    const int len = (ti + 1) * 64;
    const unsigned short* rowp =
        cpack + (size_t)4096 * ((size_t)ti * (ti + 1) / 2) + (size_t)il * len;
    const int nch = len >> 3;                  // 8..512 chunks of 8 elems

    for (int ch = tid; ch < nch; ch += 256) {
        union { bf16x8 v; unsigned short s[8]; } cv;
        cv.v = *(const bf16x8*)(rowp + ch * 8);
        union { int4 a[2]; int j[8]; } ji;
        ji.a[0] = *(const int4*)(idx + ch * 8);
        ji.a[1] = *(const int4*)(idx + ch * 8 + 4);
        #pragma unroll
        for (int i = 0; i < 8; ++i) {
            const int v = ji.j[i] - lo;
            if ((unsigned)v < (unsigned)VQ) {
                const float f = bf2f(cv.s[i]);
                if (f != 0.0f) atomicAdd(&hist[v], f);
            }
        }
    }
    __syncthreads();

    f32x4* orow = (f32x4*)(out + (size_t)t * VOCAB + lo);
    for (int v = tid; v < VQ / 4; v += 256)
        __builtin_nontemporal_store(hist4[v], orow + v);
}

// ---------------------------------------------------------------------------
extern "C" void kernel_launch(void* const* d_in, const int* in_sizes, int n_in,
                              void* d_out, int out_size, void* d_ws, size_t ws_size,
                              hipStream_t stream)
{
    const float* x   = (const float*)d_in[0];
    const int*   idx = (const int*)d_in[1];
    const float* Wq  = (const float*)d_in[2];
    const float* Wk  = (const float*)d_in[3];
    float* out = (float*)d_out;

    // ws: xb 8MB | WT 1MB | qk 4MB | cpack 17MB  => ~30MB
    unsigned short* xb = (unsigned short*)d_ws;
    unsigned short* WT = xb + (size_t)T * C;
    unsigned short* qk = WT + (size_t)2 * D * C;
    unsigned short* cpack = qk + (size_t)T * 2 * D;

    prep_kernel<<<dim3(2048 + 128), 256, 0, stream>>>(x, Wq, Wk, xb, WT);
    qk_mfma_kernel<<<dim3(T / 64, (2 * D) / 64), 256, 0, stream>>>(xb, WT, qk);
    qkt_mfma_kernel<<<dim3(NTILES), 256, 0, stream>>>(qk, cpack);
    row_scatter_kernel<<<dim3(T, 4), 256, 0, stream>>>(cpack, idx, out);
}